// Round 7
// baseline (207.294 us; speedup 1.0000x reference)
//
#include <hip/hip_runtime.h>

#define B_DIM 4096
#define H_DIM 1024
#define K_DIM 2048   // IN + H
#define NTILE (K_DIM / 64)

typedef unsigned short u16;
typedef unsigned int u32;
typedef __attribute__((ext_vector_type(8))) short short8;
typedef __attribute__((ext_vector_type(4))) float f32x4;
typedef __attribute__((ext_vector_type(16))) float f32x16;

typedef const __attribute__((address_space(1))) void* gas_ptr;
typedef __attribute__((address_space(3))) void* las_ptr;

#define WT_ELEMS (4 * H_DIM * K_DIM)       // 8.39M u16
#define AC_ELEMS (B_DIM * K_DIM)           // 8.39M u16
#define WS_NEEDED ((size_t)(WT_ELEMS + AC_ELEMS) * 2)   // 33.55 MB

__device__ __forceinline__ void gl_lds16(const u16* g, u16* l) {
    __builtin_amdgcn_global_load_lds((gas_ptr)g, (las_ptr)l, 16, 0, 0);
}
__device__ __forceinline__ float bf2f(u16 v) {
    return __builtin_bit_cast(float, (u32)((u32)v << 16));
}
__device__ __forceinline__ u16 f2bf(float f) {
    u32 u = __builtin_bit_cast(u32, f);
    return (u16)((u + 0x7fffu + ((u >> 16) & 1u)) >> 16);
}
__device__ __forceinline__ float sigm(float x) { return 1.0f / (1.0f + __expf(-x)); }
__device__ __forceinline__ float tanh_f(float x) { return 1.0f - 2.0f / (__expf(2.0f * x) + 1.0f); }

// ---------- consolidated prep (round-5/6 verified): 1024 blocks ----------
__global__ __launch_bounds__(256) void prep_all(const float* __restrict__ x, const float* __restrict__ h,
                                                const float* __restrict__ Wf, const float* __restrict__ Wi,
                                                const float* __restrict__ Wg, const float* __restrict__ Wo,
                                                u16* __restrict__ A, u16* __restrict__ Wt) {
    const int t = threadIdx.x;
    if (blockIdx.x < 512) {
#pragma unroll
        for (int it = 0; it < 8; ++it) {
            int e = it * (512 * 256 * 8) + (blockIdx.x * 256 + t) * 8;
            int m = e >> 11, c = e & 2047;
            const float* src = (c < 1024) ? (x + (size_t)m * 1024 + c)
                                          : (h + (size_t)m * 1024 + (c - 1024));
            float4 v0 = ((const float4*)src)[0], v1 = ((const float4*)src)[1];
            short8 q;
            q[0] = (short)f2bf(v0.x); q[1] = (short)f2bf(v0.y); q[2] = (short)f2bf(v0.z); q[3] = (short)f2bf(v0.w);
            q[4] = (short)f2bf(v1.x); q[5] = (short)f2bf(v1.y); q[6] = (short)f2bf(v1.z); q[7] = (short)f2bf(v1.w);
            *(short8*)(A + e) = q;
        }
    } else {
        const int id = (blockIdx.x - 512) * 4 + (t >> 6);   // one 64x64 tile per wave
        const int l = t & 63;
        const int k0 = (id & 31) * 64, n0 = ((id >> 5) & 15) * 64, g = id >> 9;
        const float* W = (g == 0) ? Wf : (g == 1) ? Wi : (g == 2) ? Wg : Wo;
        const int no = (l & 7) * 8;
        const int ko = (l >> 3) * 8;
        float f[8][8];
#pragma unroll
        for (int j = 0; j < 8; ++j) {
            const float4* s = (const float4*)(W + (size_t)(k0 + ko + j) * H_DIM + n0 + no);
            float4 a = s[0], b = s[1];
            f[j][0] = a.x; f[j][1] = a.y; f[j][2] = a.z; f[j][3] = a.w;
            f[j][4] = b.x; f[j][5] = b.y; f[j][6] = b.z; f[j][7] = b.w;
        }
        u16* dst0 = Wt + (size_t)g * ((size_t)H_DIM * K_DIM) + (size_t)(n0 + no) * K_DIM + k0 + ko;
#pragma unroll
        for (int w2 = 0; w2 < 8; ++w2) {
            short8 q;
#pragma unroll
            for (int j = 0; j < 8; ++j) q[j] = (short)f2bf(f[j][w2]);
            *(short8*)(dst0 + (size_t)w2 * K_DIM) = q;
        }
    }
}

// ---------- main fused GEMM + LSTM: 32x32x16 MFMA, 8-phase counted-vmcnt ----------
// Block: 256 m x (4 gates x 64 h-cols), 512 thr = 8 waves as 4 wr (64 m each) x 2 wc
// (32 h-cols each). Per wave: 2 m-tiles x 4 gates = 8 MFMA tiles of 32x32,
// acc = [2][4] f32x16 = 128 VGPR. BK=64 = 2 k-halves x (K=16 x 2 k-steps).
// Fragment maps (generalizing the verified 16x16x32 kernel): A/B lane = row/col l&31,
// k8-group = l>>5; C/D: col = lane&31, row = (reg&3)+8*(reg>>2)+4*(lane>>5) [m74/m101].
// LDS: A [256 m][64 k] slot-swz (unchanged); B 8 n-tiles [nt = g*2+hh][32 c][64 k],
// slot = k8 ^ (c&7). Staging halves keep gates {0,1}/{2,3} -> vmcnt ledger identical
// to the verified round-3/6 kernel: enter kt with [Bg23(kt)]=2; q0 +Ah0, close vm2
// retires Bg23(kt) (read in q1); q1 +Ah1; q2 +Bg01; q3 +Bg23, close vm2 retires
// Ah0/Ah1/Bg01(kt+1). Minimal pinning (round-6): no manual lgkmcnt, one anti-sink
// pin at q3. Phases: q0 g01xkh0 (8 rd, 8 MFMA), q1 g23xkh0 (4 rd, A-frags reused),
// q2 g01xkh1, q3 g23xkh1.
#define PH_OPEN                                                  \
    __builtin_amdgcn_s_barrier();                                \
    __builtin_amdgcn_s_setprio(1)

#define PH_CLOSE                                                 \
    __builtin_amdgcn_s_setprio(0);                               \
    __builtin_amdgcn_s_barrier()

#define PH_CLOSE_VM2                                             \
    __builtin_amdgcn_s_setprio(0);                               \
    asm volatile("s_waitcnt vmcnt(2)" ::: "memory");             \
    __builtin_amdgcn_s_barrier()

#define PH_CLOSE_VM2_PIN                                         \
    __builtin_amdgcn_sched_barrier(0);                           \
    __builtin_amdgcn_s_setprio(0);                               \
    asm volatile("s_waitcnt vmcnt(2)" ::: "memory");             \
    __builtin_amdgcn_s_barrier()

#define PH_CLOSE_VM0                                             \
    __builtin_amdgcn_s_setprio(0);                               \
    asm volatile("s_waitcnt vmcnt(0)" ::: "memory");             \
    __builtin_amdgcn_s_barrier()

#define STG_A(NB, H)                                                              \
    gl_lds16(pa[H][0], &sm[NB][(H) * 8192 + t * 8]);        pa[H][0] += 64;       \
    gl_lds16(pa[H][1], &sm[NB][(H) * 8192 + 4096 + t * 8]); pa[H][1] += 64;

#define STG_B(NB, H)                                                                      \
    gl_lds16(pb[H][0], &sm[NB][16384 + (H) * 8192 + t * 8]);        pb[H][0] += 64;       \
    gl_lds16(pb[H][1], &sm[NB][16384 + (H) * 8192 + 4096 + t * 8]); pb[H][1] += 64;

// A-frag: rows wr*64 + mt*32 + (l&31), k8 = KH*4 + ks*2 + (l>>5), slot = k8 ^ (l&7)
#define RD_A32(CB, KH)                                                                     \
    _Pragma("unroll") for (int mt = 0; mt < 2; ++mt)                                       \
    _Pragma("unroll") for (int ks = 0; ks < 2; ++ks)                                       \
        afr[mt * 2 + ks] = *(const short8*)&sm[CB][(wr * 64 + mt * 32 + l31) * 64 +        \
                                                   (((KH) * 4 + ks * 2 + hi) ^ v7) * 8];

// B-frag: tile nt = (GP*2+GL)*2 + wc, col c = l&31, same k8/slot form
#define RD_B32(CB, GP, GL, KH)                                                             \
    _Pragma("unroll") for (int ks = 0; ks < 2; ++ks)                                       \
        bfr[(GL) * 2 + ks] = *(const short8*)&sm[CB][16384 +                               \
            (((GP) * 2 + (GL)) * 2 + wc) * 2048 + l31 * 64 +                               \
            (((KH) * 4 + ks * 2 + hi) ^ v7) * 8];

#define MFMA_Q(GP)                                                                         \
    _Pragma("unroll") for (int mt = 0; mt < 2; ++mt)                                       \
    _Pragma("unroll") for (int ks = 0; ks < 2; ++ks) {                                     \
        acc[mt][2 * (GP)]     = __builtin_amdgcn_mfma_f32_32x32x16_bf16(                   \
            afr[mt * 2 + ks], bfr[0 * 2 + ks], acc[mt][2 * (GP)], 0, 0, 0);                \
        acc[mt][2 * (GP) + 1] = __builtin_amdgcn_mfma_f32_32x32x16_bf16(                   \
            afr[mt * 2 + ks], bfr[1 * 2 + ks], acc[mt][2 * (GP) + 1], 0, 0, 0);            \
    }

__global__ __launch_bounds__(512, 2) void lstm_gemm(
    const u16* __restrict__ A, const u16* __restrict__ Wt, const float* __restrict__ c_prev,
    const float* __restrict__ bf_, const float* __restrict__ bi_,
    const float* __restrict__ bg_, const float* __restrict__ bo_,
    float* __restrict__ out) {
    // per buffer: [0,16384) A: m*64 + slot*8 ; [16384,32768) B: nt*2048 + c*64 + slot*8
    __shared__ u16 sm[2][32768];   // 128 KiB total

    const int t = threadIdx.x;
    const int w = t >> 6;
    const int l = t & 63;
    const int l31 = l & 31;
    const int hi = l >> 5;
    const int v7 = l & 7;
    const int wr = w >> 1;          // 0..3: 64-row m-quarter
    const int wc = w & 1;           // 0..1: 32-col h-half
    const int m0 = blockIdx.x * 256;
    const int j0 = blockIdx.y * 64;

    f32x16 acc[2][4];               // [m-tile][gate]
#pragma unroll
    for (int mt = 0; mt < 2; ++mt)
#pragma unroll
        for (int g = 0; g < 4; ++g)
            acc[mt][g] = (f32x16){0.f, 0.f, 0.f, 0.f, 0.f, 0.f, 0.f, 0.f,
                                  0.f, 0.f, 0.f, 0.f, 0.f, 0.f, 0.f, 0.f};

    // Staging source pointers, pre-swizzled (advance by 64 u16 per K-tile).
    // A half h = m-rows [h*128,+128); B half h = gates {2h, 2h+1} (nt 4h..4h+3).
    const u16* pa[2][2];
    const u16* pb[2][2];
#pragma unroll
    for (int h = 0; h < 2; ++h)
#pragma unroll
        for (int i = 0; i < 2; ++i) {
            int e = h * 8192 + (i * 512 + t) * 8;
            int m = e >> 6, sl = (e >> 3) & 7;
            pa[h][i] = A + (size_t)(m0 + m) * K_DIM + ((sl ^ (m & 7)) * 8);
            int nt = e >> 11, c = (e >> 6) & 31;
            int g = nt >> 1, hh = nt & 1;
            pb[h][i] = Wt + (size_t)g * ((size_t)H_DIM * K_DIM) +
                       (size_t)(j0 + hh * 32 + c) * K_DIM + ((sl ^ (c & 7)) * 8);
        }

    short8 afr[4], bfr[4];

    // prologue: stage tile 0 into buf 0 (issue order: A-h0, A-h1, B-g01, B-g23)
    STG_A(0, 0); STG_A(0, 1); STG_B(0, 0); STG_B(0, 1);
    asm volatile("s_waitcnt vmcnt(2)" ::: "memory");   // A + B-g01 landed; B-g23 in flight
    __builtin_amdgcn_s_barrier();

    for (int kt = 0; kt < NTILE - 1; ++kt) {
        const int cb = kt & 1, nb = cb ^ 1;
        // ---- q0: gates 0,1 x k-half 0 ----
        RD_A32(cb, 0);
        RD_B32(cb, 0, 0, 0); RD_B32(cb, 0, 1, 0);
        STG_A(nb, 0);
        PH_OPEN;
        MFMA_Q(0);
        PH_CLOSE_VM2;        // B-g23(kt) landed; A-h0(kt+1) in flight
        // ---- q1: gates 2,3 x k-half 0 (A-frags reused) ----
        RD_B32(cb, 1, 0, 0); RD_B32(cb, 1, 1, 0);
        STG_A(nb, 1);
        PH_OPEN;
        MFMA_Q(1);
        PH_CLOSE;
        // ---- q2: gates 0,1 x k-half 1 ----
        RD_A32(cb, 1);
        RD_B32(cb, 0, 0, 1); RD_B32(cb, 0, 1, 1);
        STG_B(nb, 0);
        PH_OPEN;
        MFMA_Q(0);
        PH_CLOSE;
        // ---- q3: gates 2,3 x k-half 1 ----
        RD_B32(cb, 1, 0, 1); RD_B32(cb, 1, 1, 1);
        STG_B(nb, 1);
        PH_OPEN;
        MFMA_Q(1);
        PH_CLOSE_VM2_PIN;    // A(kt+1) + B-g01(kt+1) landed; B-g23(kt+1) in flight
    }
    {   // peeled last tile (cb = 1), no staging
        const int cb = (NTILE - 1) & 1;
        RD_A32(cb, 0);
        RD_B32(cb, 0, 0, 0); RD_B32(cb, 0, 1, 0);
        PH_OPEN;
        MFMA_Q(0);
        PH_CLOSE_VM0;        // only B-g23(last) outstanding -> full drain
        RD_B32(cb, 1, 0, 0); RD_B32(cb, 1, 1, 0);
        PH_OPEN;
        MFMA_Q(1);
        PH_CLOSE;
        RD_A32(cb, 1);
        RD_B32(cb, 0, 0, 1); RD_B32(cb, 0, 1, 1);
        PH_OPEN;
        MFMA_Q(0);
        PH_CLOSE;
        RD_B32(cb, 1, 0, 1); RD_B32(cb, 1, 1, 1);
        MFMA_Q(1);           // compiler auto-waits operands
    }

    // -------- register epilogue: all 4 gates of each output element in one lane --------
    // C/D map (32x32): col = lane&31, row = (reg&3) + 8*(reg>>2) + 4*(lane>>5)
    const int col = j0 + wc * 32 + l31;
    const float bF = bf_[col], bI = bi_[col], bG = bg_[col], bO = bo_[col];
#pragma unroll
    for (int mt = 0; mt < 2; ++mt) {
        const int rb0 = m0 + wr * 64 + mt * 32 + hi * 4;
#pragma unroll
        for (int r = 0; r < 16; ++r) {
            const int row = rb0 + (r & 3) + 8 * (r >> 2);
            size_t idx = (size_t)row * H_DIM + col;
            float cpv = c_prev[idx];
            float fv = sigm(acc[mt][0][r] + bF);
            float iv = sigm(acc[mt][1][r] + bI);
            float gv = tanh_f(acc[mt][2][r] + bG);
            float ov = sigm(acc[mt][3][r] + bO);
            float cn = fv * cpv + iv * gv;
            float hn = ov * tanh_f(cn);
            out[idx] = hn;
            out[(size_t)B_DIM * H_DIM + idx] = cn;
        }
    }
}

// ---------- fallback (verified): used only if ws too small ----------
__global__ __launch_bounds__(256) void lstm_f32(
    const float* __restrict__ x, const float* __restrict__ h_prev, const float* __restrict__ c_prev,
    const float* __restrict__ Wf, const float* __restrict__ Wi, const float* __restrict__ Wg, const float* __restrict__ Wo,
    const float* __restrict__ bf_, const float* __restrict__ bi_, const float* __restrict__ bg_, const float* __restrict__ bo_,
    float* __restrict__ out) {
    __shared__ u16 smem[16384];
    u16* sA = smem;
    u16* sB = smem + 4096;

    const int t = threadIdx.x;
    const int w = t >> 6;
    const int l = t & 63;
    const int quad = l >> 4;
    const int l15 = l & 15;
    const int wr = w >> 1;
    const int wc = w & 1;
    const int m0 = blockIdx.x * 128;
    const int j0 = blockIdx.y * 32;

    const int arow = t >> 1;
    const int akh = (t & 1) * 16;
    const int r7 = t & 127;
    const int bk = r7 >> 2;
    const int bn8 = (r7 & 3) * 8;
    const int kswz = ((((bk >> 3) ^ (bn8 >> 3)) << 3) | (bk & 7));
    const float* WpA = (t < 128) ? Wf : Wi;
    const float* WpB = (t < 128) ? Wg : Wo;
    const int gA = (t >> 7);
    const int gB = 2 + (t >> 7);

    f32x4 acc[2][4][2];
#pragma unroll
    for (int gi = 0; gi < 2; ++gi)
#pragma unroll
        for (int mi = 0; mi < 4; ++mi)
#pragma unroll
            for (int ni = 0; ni < 2; ++ni)
                acc[gi][mi][ni] = (f32x4){0.f, 0.f, 0.f, 0.f};

    for (int kt = 0; kt < K_DIM / 32; ++kt) {
        const float* srcA = (kt < 32) ? x : h_prev;
        const int koff = (kt & 31) * 32;
        __syncthreads();

        const float4* ap = (const float4*)(srcA + (size_t)(m0 + arow) * H_DIM + koff + akh);
        float4 a0 = ap[0], a1 = ap[1], a2 = ap[2], a3 = ap[3];
        short8 p0, p1;
        p0[0] = (short)f2bf(a0.x); p0[1] = (short)f2bf(a0.y); p0[2] = (short)f2bf(a0.z); p0[3] = (short)f2bf(a0.w);
        p0[4] = (short)f2bf(a1.x); p0[5] = (short)f2bf(a1.y); p0[6] = (short)f2bf(a1.z); p0[7] = (short)f2bf(a1.w);
        p1[0] = (short)f2bf(a2.x); p1[1] = (short)f2bf(a2.y); p1[2] = (short)f2bf(a2.z); p1[3] = (short)f2bf(a2.w);
        p1[4] = (short)f2bf(a3.x); p1[5] = (short)f2bf(a3.y); p1[6] = (short)f2bf(a3.z); p1[7] = (short)f2bf(a3.w);
        *(short8*)(sA + arow * 32 + akh) = p0;
        *(short8*)(sA + arow * 32 + akh + 8) = p1;

        const float* gpA = WpA + (size_t)(kt * 32 + bk) * H_DIM + j0 + bn8;
        const float* gpB = WpB + (size_t)(kt * 32 + bk) * H_DIM + j0 + bn8;
        float4 c0 = *(const float4*)gpA, c1 = *(const float4*)(gpA + 4);
        float4 d0 = *(const float4*)gpB, d1 = *(const float4*)(gpB + 4);
        sB[gA * 1024 + (bn8 + 0) * 32 + kswz] = f2bf(c0.x);
        sB[gA * 1024 + (bn8 + 1) * 32 + kswz] = f2bf(c0.y);
        sB[gA * 1024 + (bn8 + 2) * 32 + kswz] = f2bf(c0.z);
        sB[gA * 1024 + (bn8 + 3) * 32 + kswz] = f2bf(c0.w);
        sB[gA * 1024 + (bn8 + 4) * 32 + kswz] = f2bf(c1.x);
        sB[gA * 1024 + (bn8 + 5) * 32 + kswz] = f2bf(c1.y);
        sB[gA * 1024 + (bn8 + 6) * 32 + kswz] = f2bf(c1.z);
        sB[gA * 1024 + (bn8 + 7) * 32 + kswz] = f2bf(c1.w);
        sB[gB * 1024 + (bn8 + 0) * 32 + kswz] = f2bf(d0.x);
        sB[gB * 1024 + (bn8 + 1) * 32 + kswz] = f2bf(d0.y);
        sB[gB * 1024 + (bn8 + 2) * 32 + kswz] = f2bf(d0.z);
        sB[gB * 1024 + (bn8 + 3) * 32 + kswz] = f2bf(d0.w);
        sB[gB * 1024 + (bn8 + 4) * 32 + kswz] = f2bf(d1.x);
        sB[gB * 1024 + (bn8 + 5) * 32 + kswz] = f2bf(d1.y);
        sB[gB * 1024 + (bn8 + 6) * 32 + kswz] = f2bf(d1.z);
        sB[gB * 1024 + (bn8 + 7) * 32 + kswz] = f2bf(d1.w);
        __syncthreads();

        short8 bfr[2][2];
#pragma unroll
        for (int gi = 0; gi < 2; ++gi) {
            int g = wc * 2 + gi;
#pragma unroll
            for (int ni = 0; ni < 2; ++ni) {
                int n = ni * 16 + l15;
                bfr[gi][ni] = *(const short8*)(sB + g * 1024 + n * 32 + ((quad ^ (n >> 3)) * 8));
            }
        }
#pragma unroll
        for (int mi = 0; mi < 4; ++mi) {
            int m = wr * 64 + mi * 16 + l15;
            short8 afr = *(const short8*)(sA + m * 32 + quad * 8);
#pragma unroll
            for (int gi = 0; gi < 2; ++gi)
#pragma unroll
                for (int ni = 0; ni < 2; ++ni)
                    acc[gi][mi][ni] =
                        __builtin_amdgcn_mfma_f32_16x16x32_bf16(afr, bfr[gi][ni], acc[gi][mi][ni], 0, 0, 0);
        }
    }

    __syncthreads();
#pragma unroll
    for (int gi = 0; gi < 2; ++gi) {
        int g = wc * 2 + gi;
        const float* bp = (g == 0) ? bf_ : (g == 1) ? bi_ : (g == 2) ? bg_ : bo_;
#pragma unroll
        for (int ni = 0; ni < 2; ++ni) {
            int col = ni * 16 + l15;
            float bias = bp[j0 + col];
#pragma unroll
            for (int mi = 0; mi < 4; ++mi)
#pragma unroll
                for (int rr = 0; rr < 4; ++rr) {
                    int row = wr * 64 + mi * 16 + quad * 4 + rr;
                    float v = acc[gi][mi][ni][rr] + bias;
                    v = (g == 2) ? tanh_f(v) : sigm(v);
                    smem[g * 4096 + row * 32 + col] = f2bf(v);
                }
        }
    }
    __syncthreads();

    const int col = t & 31;
    const int rb = t >> 5;
#pragma unroll
    for (int p = 0; p < 16; ++p) {
        int row = p * 8 + rb;
        float fv = bf2f(smem[0 * 4096 + row * 32 + col]);
        float iv = bf2f(smem[1 * 4096 + row * 32 + col]);
        float gv = bf2f(smem[2 * 4096 + row * 32 + col]);
        float ov = bf2f(smem[3 * 4096 + row * 32 + col]);
        size_t oidx = (size_t)(m0 + row) * H_DIM + j0 + col;
        float cp = c_prev[oidx];
        float cn = fv * cp + iv * gv;
        float hn = ov * tanh_f(cn);
        out[oidx] = hn;
        out[(size_t)B_DIM * H_DIM + oidx] = cn;
    }
}

extern "C" void kernel_launch(void* const* d_in, const int* in_sizes, int n_in,
                              void* d_out, int out_size, void* d_ws, size_t ws_size,
                              hipStream_t stream) {
    const float* x   = (const float*)d_in[0];
    const float* hp  = (const float*)d_in[1];
    const float* cp  = (const float*)d_in[2];
    const float* Wf  = (const float*)d_in[3];
    const float* bf_ = (const float*)d_in[4];
    const float* Wi  = (const float*)d_in[5];
    const float* bi_ = (const float*)d_in[6];
    const float* Wg  = (const float*)d_in[7];
    const float* bg_ = (const float*)d_in[8];
    const float* Wo  = (const float*)d_in[9];
    const float* bo_ = (const float*)d_in[10];

    if (ws_size >= WS_NEEDED) {
        u16* Wt = (u16*)d_ws;
        u16* Ac = (u16*)d_ws + WT_ELEMS;
        prep_all<<<dim3(1024), dim3(256), 0, stream>>>(x, hp, Wf, Wi, Wg, Wo, Ac, Wt);
        lstm_gemm<<<dim3(B_DIM / 256, H_DIM / 64), dim3(512), 0, stream>>>(
            Ac, Wt, cp, bf_, bi_, bg_, bo_, (float*)d_out);
    } else {
        lstm_f32<<<dim3(B_DIM / 128, H_DIM / 32), dim3(256), 0, stream>>>(
            x, hp, cp, Wf, Wi, Wg, Wo, bf_, bi_, bg_, bo_, (float*)d_out);
    }
}

// Round 8
// 201.796 us; speedup vs baseline: 1.0272x; 1.0272x over previous
//
#include <hip/hip_runtime.h>

#define B_DIM 4096
#define H_DIM 1024
#define K_DIM 2048   // IN + H
#define NTILE (K_DIM / 64)

typedef unsigned short u16;
typedef unsigned int u32;
typedef __attribute__((ext_vector_type(8))) short short8;
typedef __attribute__((ext_vector_type(4))) float f32x4;
typedef __attribute__((ext_vector_type(16))) float f32x16;

typedef const __attribute__((address_space(1))) void* gas_ptr;
typedef __attribute__((address_space(3))) void* las_ptr;

#define WT_ELEMS (4 * H_DIM * K_DIM)       // 8.39M u16
#define AC_ELEMS (B_DIM * K_DIM)           // 8.39M u16
#define WS_NEEDED ((size_t)(WT_ELEMS + AC_ELEMS) * 2)   // 33.55 MB

__device__ __forceinline__ void gl_lds16(const u16* g, u16* l) {
    __builtin_amdgcn_global_load_lds((gas_ptr)g, (las_ptr)l, 16, 0, 0);
}
__device__ __forceinline__ float bf2f(u16 v) {
    return __builtin_bit_cast(float, (u32)((u32)v << 16));
}
__device__ __forceinline__ u16 f2bf(float f) {
    u32 u = __builtin_bit_cast(u32, f);
    return (u16)((u + 0x7fffu + ((u >> 16) & 1u)) >> 16);
}
__device__ __forceinline__ float sigm(float x) { return 1.0f / (1.0f + __expf(-x)); }
__device__ __forceinline__ float tanh_f(float x) { return 1.0f - 2.0f / (__expf(2.0f * x) + 1.0f); }

// ---------- consolidated prep (round-5/6 verified): 1024 blocks ----------
__global__ __launch_bounds__(256) void prep_all(const float* __restrict__ x, const float* __restrict__ h,
                                                const float* __restrict__ Wf, const float* __restrict__ Wi,
                                                const float* __restrict__ Wg, const float* __restrict__ Wo,
                                                u16* __restrict__ A, u16* __restrict__ Wt) {
    const int t = threadIdx.x;
    if (blockIdx.x < 512) {
#pragma unroll
        for (int it = 0; it < 8; ++it) {
            int e = it * (512 * 256 * 8) + (blockIdx.x * 256 + t) * 8;
            int m = e >> 11, c = e & 2047;
            const float* src = (c < 1024) ? (x + (size_t)m * 1024 + c)
                                          : (h + (size_t)m * 1024 + (c - 1024));
            float4 v0 = ((const float4*)src)[0], v1 = ((const float4*)src)[1];
            short8 q;
            q[0] = (short)f2bf(v0.x); q[1] = (short)f2bf(v0.y); q[2] = (short)f2bf(v0.z); q[3] = (short)f2bf(v0.w);
            q[4] = (short)f2bf(v1.x); q[5] = (short)f2bf(v1.y); q[6] = (short)f2bf(v1.z); q[7] = (short)f2bf(v1.w);
            *(short8*)(A + e) = q;
        }
    } else {
        const int id = (blockIdx.x - 512) * 4 + (t >> 6);   // one 64x64 tile per wave
        const int l = t & 63;
        const int k0 = (id & 31) * 64, n0 = ((id >> 5) & 15) * 64, g = id >> 9;
        const float* W = (g == 0) ? Wf : (g == 1) ? Wi : (g == 2) ? Wg : Wo;
        const int no = (l & 7) * 8;
        const int ko = (l >> 3) * 8;
        float f[8][8];
#pragma unroll
        for (int j = 0; j < 8; ++j) {
            const float4* s = (const float4*)(W + (size_t)(k0 + ko + j) * H_DIM + n0 + no);
            float4 a = s[0], b = s[1];
            f[j][0] = a.x; f[j][1] = a.y; f[j][2] = a.z; f[j][3] = a.w;
            f[j][4] = b.x; f[j][5] = b.y; f[j][6] = b.z; f[j][7] = b.w;
        }
        u16* dst0 = Wt + (size_t)g * ((size_t)H_DIM * K_DIM) + (size_t)(n0 + no) * K_DIM + k0 + ko;
#pragma unroll
        for (int w2 = 0; w2 < 8; ++w2) {
            short8 q;
#pragma unroll
            for (int j = 0; j < 8; ++j) q[j] = (short)f2bf(f[j][w2]);
            *(short8*)(dst0 + (size_t)w2 * K_DIM) = q;
        }
    }
}

// ---------- main fused GEMM + LSTM: 32x32x16 MFMA, 8-phase counted-vmcnt ----------
// Round-7 structure (passed; fragment maps verified) with the RANK-2 XOR SWIZZLE fix:
//   phys_slot = k8 ^ (row & 7) ^ ((row >> 3) & 3)
// applied BOTH-SIDES (pre-swizzled global source + ds_read index; rule #21).
// Why: round-7's slot = k8 ^ (row&7) left lanes {l, l+8, l+16, l+24} (same l&7, same
// l>>5) on the SAME slot -> same 4 banks, 4 different rows = 4-way conflict on every
// b128 frag read (SQ_LDS_BANK_CONFLICT 6.29M, +5 us). With the (row>>3)&3 term any
// power-of-2-strided 8-lane group hits each slot <= 2x (2-way = free, m136).
// Everything else identical to round 7: 4 wr x 2 wc waves, acc [2][4] f32x16, BK=64,
// vmcnt ledger (vm2 at q0/q3 closes, Bg23 in flight), minimal pinning, setprio.
#define PH_OPEN                                                  \
    __builtin_amdgcn_s_barrier();                                \
    __builtin_amdgcn_s_setprio(1)

#define PH_CLOSE                                                 \
    __builtin_amdgcn_s_setprio(0);                               \
    __builtin_amdgcn_s_barrier()

#define PH_CLOSE_VM2                                             \
    __builtin_amdgcn_s_setprio(0);                               \
    asm volatile("s_waitcnt vmcnt(2)" ::: "memory");             \
    __builtin_amdgcn_s_barrier()

#define PH_CLOSE_VM2_PIN                                         \
    __builtin_amdgcn_sched_barrier(0);                           \
    __builtin_amdgcn_s_setprio(0);                               \
    asm volatile("s_waitcnt vmcnt(2)" ::: "memory");             \
    __builtin_amdgcn_s_barrier()

#define PH_CLOSE_VM0                                             \
    __builtin_amdgcn_s_setprio(0);                               \
    asm volatile("s_waitcnt vmcnt(0)" ::: "memory");             \
    __builtin_amdgcn_s_barrier()

#define STG_A(NB, H)                                                              \
    gl_lds16(pa[H][0], &sm[NB][(H) * 8192 + t * 8]);        pa[H][0] += 64;       \
    gl_lds16(pa[H][1], &sm[NB][(H) * 8192 + 4096 + t * 8]); pa[H][1] += 64;

#define STG_B(NB, H)                                                                      \
    gl_lds16(pb[H][0], &sm[NB][16384 + (H) * 8192 + t * 8]);        pb[H][0] += 64;       \
    gl_lds16(pb[H][1], &sm[NB][16384 + (H) * 8192 + 4096 + t * 8]); pb[H][1] += 64;

// A-frag: rows wr*64 + mt*32 + l31; slot = k8 ^ v7 ^ q2   (q2 = (l31>>3)&3)
#define RD_A32(CB, KH)                                                                     \
    _Pragma("unroll") for (int mt = 0; mt < 2; ++mt)                                       \
    _Pragma("unroll") for (int ks = 0; ks < 2; ++ks)                                       \
        afr[mt * 2 + ks] = *(const short8*)&sm[CB][(wr * 64 + mt * 32 + l31) * 64 +        \
                                                   ((((KH) * 4 + ks * 2 + hi) ^ v7 ^ q2) * 8)];

// B-frag: tile nt = (GP*2+GL)*2 + wc, col row = l31, same slot form
#define RD_B32(CB, GP, GL, KH)                                                             \
    _Pragma("unroll") for (int ks = 0; ks < 2; ++ks)                                       \
        bfr[(GL) * 2 + ks] = *(const short8*)&sm[CB][16384 +                               \
            (((GP) * 2 + (GL)) * 2 + wc) * 2048 + l31 * 64 +                               \
            ((((KH) * 4 + ks * 2 + hi) ^ v7 ^ q2) * 8)];

#define MFMA_Q(GP)                                                                         \
    _Pragma("unroll") for (int mt = 0; mt < 2; ++mt)                                       \
    _Pragma("unroll") for (int ks = 0; ks < 2; ++ks) {                                     \
        acc[mt][2 * (GP)]     = __builtin_amdgcn_mfma_f32_32x32x16_bf16(                   \
            afr[mt * 2 + ks], bfr[0 * 2 + ks], acc[mt][2 * (GP)], 0, 0, 0);                \
        acc[mt][2 * (GP) + 1] = __builtin_amdgcn_mfma_f32_32x32x16_bf16(                   \
            afr[mt * 2 + ks], bfr[1 * 2 + ks], acc[mt][2 * (GP) + 1], 0, 0, 0);            \
    }

__global__ __launch_bounds__(512, 2) void lstm_gemm(
    const u16* __restrict__ A, const u16* __restrict__ Wt, const float* __restrict__ c_prev,
    const float* __restrict__ bf_, const float* __restrict__ bi_,
    const float* __restrict__ bg_, const float* __restrict__ bo_,
    float* __restrict__ out) {
    // per buffer: [0,16384) A: m*64 + slot*8 ; [16384,32768) B: nt*2048 + c*64 + slot*8
    __shared__ u16 sm[2][32768];   // 128 KiB total

    const int t = threadIdx.x;
    const int w = t >> 6;
    const int l = t & 63;
    const int l31 = l & 31;
    const int hi = l >> 5;
    const int v7 = l & 7;
    const int q2 = (l31 >> 3) & 3;
    const int wr = w >> 1;          // 0..3: 64-row m-quarter
    const int wc = w & 1;           // 0..1: 32-col h-half
    const int m0 = blockIdx.x * 256;
    const int j0 = blockIdx.y * 64;

    f32x16 acc[2][4];               // [m-tile][gate]
#pragma unroll
    for (int mt = 0; mt < 2; ++mt)
#pragma unroll
        for (int g = 0; g < 4; ++g)
            acc[mt][g] = (f32x16){0.f, 0.f, 0.f, 0.f, 0.f, 0.f, 0.f, 0.f,
                                  0.f, 0.f, 0.f, 0.f, 0.f, 0.f, 0.f, 0.f};

    // Staging source pointers, pre-swizzled with the SAME rank-2 swizzle
    // (advance by 64 u16 per K-tile). A half h = m-rows [h*128,+128);
    // B half h = gates {2h, 2h+1} (nt 4h..4h+3).
    const u16* pa[2][2];
    const u16* pb[2][2];
#pragma unroll
    for (int h = 0; h < 2; ++h)
#pragma unroll
        for (int i = 0; i < 2; ++i) {
            int e = h * 8192 + (i * 512 + t) * 8;
            int m = e >> 6, sl = (e >> 3) & 7;
            pa[h][i] = A + (size_t)(m0 + m) * K_DIM +
                       ((sl ^ (m & 7) ^ ((m >> 3) & 3)) * 8);
            int nt = e >> 11, c = (e >> 6) & 31;
            int g = nt >> 1, hh = nt & 1;
            pb[h][i] = Wt + (size_t)g * ((size_t)H_DIM * K_DIM) +
                       (size_t)(j0 + hh * 32 + c) * K_DIM +
                       ((sl ^ (c & 7) ^ ((c >> 3) & 3)) * 8);
        }

    short8 afr[4], bfr[4];

    // prologue: stage tile 0 into buf 0 (issue order: A-h0, A-h1, B-g01, B-g23)
    STG_A(0, 0); STG_A(0, 1); STG_B(0, 0); STG_B(0, 1);
    asm volatile("s_waitcnt vmcnt(2)" ::: "memory");   // A + B-g01 landed; B-g23 in flight
    __builtin_amdgcn_s_barrier();

    for (int kt = 0; kt < NTILE - 1; ++kt) {
        const int cb = kt & 1, nb = cb ^ 1;
        // ---- q0: gates 0,1 x k-half 0 ----
        RD_A32(cb, 0);
        RD_B32(cb, 0, 0, 0); RD_B32(cb, 0, 1, 0);
        STG_A(nb, 0);
        PH_OPEN;
        MFMA_Q(0);
        PH_CLOSE_VM2;        // B-g23(kt) landed; A-h0(kt+1) in flight
        // ---- q1: gates 2,3 x k-half 0 (A-frags reused) ----
        RD_B32(cb, 1, 0, 0); RD_B32(cb, 1, 1, 0);
        STG_A(nb, 1);
        PH_OPEN;
        MFMA_Q(1);
        PH_CLOSE;
        // ---- q2: gates 0,1 x k-half 1 ----
        RD_A32(cb, 1);
        RD_B32(cb, 0, 0, 1); RD_B32(cb, 0, 1, 1);
        STG_B(nb, 0);
        PH_OPEN;
        MFMA_Q(0);
        PH_CLOSE;
        // ---- q3: gates 2,3 x k-half 1 ----
        RD_B32(cb, 1, 0, 1); RD_B32(cb, 1, 1, 1);
        STG_B(nb, 1);
        PH_OPEN;
        MFMA_Q(1);
        PH_CLOSE_VM2_PIN;    // A(kt+1) + B-g01(kt+1) landed; B-g23(kt+1) in flight
    }
    {   // peeled last tile (cb = 1), no staging
        const int cb = (NTILE - 1) & 1;
        RD_A32(cb, 0);
        RD_B32(cb, 0, 0, 0); RD_B32(cb, 0, 1, 0);
        PH_OPEN;
        MFMA_Q(0);
        PH_CLOSE_VM0;        // only B-g23(last) outstanding -> full drain
        RD_B32(cb, 1, 0, 0); RD_B32(cb, 1, 1, 0);
        PH_OPEN;
        MFMA_Q(1);
        PH_CLOSE;
        RD_A32(cb, 1);
        RD_B32(cb, 0, 0, 1); RD_B32(cb, 0, 1, 1);
        PH_OPEN;
        MFMA_Q(0);
        PH_CLOSE;
        RD_B32(cb, 1, 0, 1); RD_B32(cb, 1, 1, 1);
        MFMA_Q(1);           // compiler auto-waits operands
    }

    // -------- register epilogue: all 4 gates of each output element in one lane --------
    // C/D map (32x32): col = lane&31, row = (reg&3) + 8*(reg>>2) + 4*(lane>>5)
    const int col = j0 + wc * 32 + l31;
    const float bF = bf_[col], bI = bi_[col], bG = bg_[col], bO = bo_[col];
#pragma unroll
    for (int mt = 0; mt < 2; ++mt) {
        const int rb0 = m0 + wr * 64 + mt * 32 + hi * 4;
#pragma unroll
        for (int r = 0; r < 16; ++r) {
            const int row = rb0 + (r & 3) + 8 * (r >> 2);
            size_t idx = (size_t)row * H_DIM + col;
            float cpv = c_prev[idx];
            float fv = sigm(acc[mt][0][r] + bF);
            float iv = sigm(acc[mt][1][r] + bI);
            float gv = tanh_f(acc[mt][2][r] + bG);
            float ov = sigm(acc[mt][3][r] + bO);
            float cn = fv * cpv + iv * gv;
            float hn = ov * tanh_f(cn);
            out[idx] = hn;
            out[(size_t)B_DIM * H_DIM + idx] = cn;
        }
    }
}

// ---------- fallback (verified): used only if ws too small ----------
__global__ __launch_bounds__(256) void lstm_f32(
    const float* __restrict__ x, const float* __restrict__ h_prev, const float* __restrict__ c_prev,
    const float* __restrict__ Wf, const float* __restrict__ Wi, const float* __restrict__ Wg, const float* __restrict__ Wo,
    const float* __restrict__ bf_, const float* __restrict__ bi_, const float* __restrict__ bg_, const float* __restrict__ bo_,
    float* __restrict__ out) {
    __shared__ u16 smem[16384];
    u16* sA = smem;
    u16* sB = smem + 4096;

    const int t = threadIdx.x;
    const int w = t >> 6;
    const int l = t & 63;
    const int quad = l >> 4;
    const int l15 = l & 15;
    const int wr = w >> 1;
    const int wc = w & 1;
    const int m0 = blockIdx.x * 128;
    const int j0 = blockIdx.y * 32;

    const int arow = t >> 1;
    const int akh = (t & 1) * 16;
    const int r7 = t & 127;
    const int bk = r7 >> 2;
    const int bn8 = (r7 & 3) * 8;
    const int kswz = ((((bk >> 3) ^ (bn8 >> 3)) << 3) | (bk & 7));
    const float* WpA = (t < 128) ? Wf : Wi;
    const float* WpB = (t < 128) ? Wg : Wo;
    const int gA = (t >> 7);
    const int gB = 2 + (t >> 7);

    f32x4 acc[2][4][2];
#pragma unroll
    for (int gi = 0; gi < 2; ++gi)
#pragma unroll
        for (int mi = 0; mi < 4; ++mi)
#pragma unroll
            for (int ni = 0; ni < 2; ++ni)
                acc[gi][mi][ni] = (f32x4){0.f, 0.f, 0.f, 0.f};

    for (int kt = 0; kt < K_DIM / 32; ++kt) {
        const float* srcA = (kt < 32) ? x : h_prev;
        const int koff = (kt & 31) * 32;
        __syncthreads();

        const float4* ap = (const float4*)(srcA + (size_t)(m0 + arow) * H_DIM + koff + akh);
        float4 a0 = ap[0], a1 = ap[1], a2 = ap[2], a3 = ap[3];
        short8 p0, p1;
        p0[0] = (short)f2bf(a0.x); p0[1] = (short)f2bf(a0.y); p0[2] = (short)f2bf(a0.z); p0[3] = (short)f2bf(a0.w);
        p0[4] = (short)f2bf(a1.x); p0[5] = (short)f2bf(a1.y); p0[6] = (short)f2bf(a1.z); p0[7] = (short)f2bf(a1.w);
        p1[0] = (short)f2bf(a2.x); p1[1] = (short)f2bf(a2.y); p1[2] = (short)f2bf(a2.z); p1[3] = (short)f2bf(a2.w);
        p1[4] = (short)f2bf(a3.x); p1[5] = (short)f2bf(a3.y); p1[6] = (short)f2bf(a3.z); p1[7] = (short)f2bf(a3.w);
        *(short8*)(sA + arow * 32 + akh) = p0;
        *(short8*)(sA + arow * 32 + akh + 8) = p1;

        const float* gpA = WpA + (size_t)(kt * 32 + bk) * H_DIM + j0 + bn8;
        const float* gpB = WpB + (size_t)(kt * 32 + bk) * H_DIM + j0 + bn8;
        float4 c0 = *(const float4*)gpA, c1 = *(const float4*)(gpA + 4);
        float4 d0 = *(const float4*)gpB, d1 = *(const float4*)(gpB + 4);
        sB[gA * 1024 + (bn8 + 0) * 32 + kswz] = f2bf(c0.x);
        sB[gA * 1024 + (bn8 + 1) * 32 + kswz] = f2bf(c0.y);
        sB[gA * 1024 + (bn8 + 2) * 32 + kswz] = f2bf(c0.z);
        sB[gA * 1024 + (bn8 + 3) * 32 + kswz] = f2bf(c0.w);
        sB[gA * 1024 + (bn8 + 4) * 32 + kswz] = f2bf(c1.x);
        sB[gA * 1024 + (bn8 + 5) * 32 + kswz] = f2bf(c1.y);
        sB[gA * 1024 + (bn8 + 6) * 32 + kswz] = f2bf(c1.z);
        sB[gA * 1024 + (bn8 + 7) * 32 + kswz] = f2bf(c1.w);
        sB[gB * 1024 + (bn8 + 0) * 32 + kswz] = f2bf(d0.x);
        sB[gB * 1024 + (bn8 + 1) * 32 + kswz] = f2bf(d0.y);
        sB[gB * 1024 + (bn8 + 2) * 32 + kswz] = f2bf(d0.z);
        sB[gB * 1024 + (bn8 + 3) * 32 + kswz] = f2bf(d0.w);
        sB[gB * 1024 + (bn8 + 4) * 32 + kswz] = f2bf(d1.x);
        sB[gB * 1024 + (bn8 + 5) * 32 + kswz] = f2bf(d1.y);
        sB[gB * 1024 + (bn8 + 6) * 32 + kswz] = f2bf(d1.z);
        sB[gB * 1024 + (bn8 + 7) * 32 + kswz] = f2bf(d1.w);
        __syncthreads();

        short8 bfr[2][2];
#pragma unroll
        for (int gi = 0; gi < 2; ++gi) {
            int g = wc * 2 + gi;
#pragma unroll
            for (int ni = 0; ni < 2; ++ni) {
                int n = ni * 16 + l15;
                bfr[gi][ni] = *(const short8*)(sB + g * 1024 + n * 32 + ((quad ^ (n >> 3)) * 8));
            }
        }
#pragma unroll
        for (int mi = 0; mi < 4; ++mi) {
            int m = wr * 64 + mi * 16 + l15;
            short8 afr = *(const short8*)(sA + m * 32 + quad * 8);
#pragma unroll
            for (int gi = 0; gi < 2; ++gi)
#pragma unroll
                for (int ni = 0; ni < 2; ++ni)
                    acc[gi][mi][ni] =
                        __builtin_amdgcn_mfma_f32_16x16x32_bf16(afr, bfr[gi][ni], acc[gi][mi][ni], 0, 0, 0);
        }
    }

    __syncthreads();
#pragma unroll
    for (int gi = 0; gi < 2; ++gi) {
        int g = wc * 2 + gi;
        const float* bp = (g == 0) ? bf_ : (g == 1) ? bi_ : (g == 2) ? bg_ : bo_;
#pragma unroll
        for (int ni = 0; ni < 2; ++ni) {
            int col = ni * 16 + l15;
            float bias = bp[j0 + col];
#pragma unroll
            for (int mi = 0; mi < 4; ++mi)
#pragma unroll
                for (int rr = 0; rr < 4; ++rr) {
                    int row = wr * 64 + mi * 16 + quad * 4 + rr;
                    float v = acc[gi][mi][ni][rr] + bias;
                    v = (g == 2) ? tanh_f(v) : sigm(v);
                    smem[g * 4096 + row * 32 + col] = f2bf(v);
                }
        }
    }
    __syncthreads();

    const int col = t & 31;
    const int rb = t >> 5;
#pragma unroll
    for (int p = 0; p < 16; ++p) {
        int row = p * 8 + rb;
        float fv = bf2f(smem[0 * 4096 + row * 32 + col]);
        float iv = bf2f(smem[1 * 4096 + row * 32 + col]);
        float gv = bf2f(smem[2 * 4096 + row * 32 + col]);
        float ov = bf2f(smem[3 * 4096 + row * 32 + col]);
        size_t oidx = (size_t)(m0 + row) * H_DIM + j0 + col;
        float cp = c_prev[oidx];
        float cn = fv * cp + iv * gv;
        float hn = ov * tanh_f(cn);
        out[oidx] = hn;
        out[(size_t)B_DIM * H_DIM + oidx] = cn;
    }
}

extern "C" void kernel_launch(void* const* d_in, const int* in_sizes, int n_in,
                              void* d_out, int out_size, void* d_ws, size_t ws_size,
                              hipStream_t stream) {
    const float* x   = (const float*)d_in[0];
    const float* hp  = (const float*)d_in[1];
    const float* cp  = (const float*)d_in[2];
    const float* Wf  = (const float*)d_in[3];
    const float* bf_ = (const float*)d_in[4];
    const float* Wi  = (const float*)d_in[5];
    const float* bi_ = (const float*)d_in[6];
    const float* Wg  = (const float*)d_in[7];
    const float* bg_ = (const float*)d_in[8];
    const float* Wo  = (const float*)d_in[9];
    const float* bo_ = (const float*)d_in[10];

    if (ws_size >= WS_NEEDED) {
        u16* Wt = (u16*)d_ws;
        u16* Ac = (u16*)d_ws + WT_ELEMS;
        prep_all<<<dim3(1024), dim3(256), 0, stream>>>(x, hp, Wf, Wi, Wg, Wo, Ac, Wt);
        lstm_gemm<<<dim3(B_DIM / 256, H_DIM / 64), dim3(512), 0, stream>>>(
            Ac, Wt, cp, bf_, bi_, bg_, bo_, (float*)d_out);
    } else {
        lstm_f32<<<dim3(B_DIM / 128, H_DIM / 32), dim3(256), 0, stream>>>(
            x, hp, cp, Wf, Wi, Wg, Wo, bf_, bi_, bg_, bo_, (float*)d_out);
    }
}